// Round 4
// baseline (695.297 us; speedup 1.0000x reference)
//
#include <hip/hip_runtime.h>
#include <hip/hip_bf16.h>

typedef __bf16 bf16_t;
typedef __bf16 bf16x4 __attribute__((ext_vector_type(4)));
typedef __bf16 bf16x8 __attribute__((ext_vector_type(8)));
typedef float f32x4 __attribute__((ext_vector_type(4)));

static constexpr int BB    = 2;
static constexpr int SEQ   = 2048;
static constexpr int DM    = 1024;   // D == INNER
static constexpr int NHEAD = 16;
static constexpr int HD    = 64;
static constexpr float L2E = 1.4426950408889634f;

__device__ __forceinline__ bf16x8 ld8(const bf16_t* p) {
  return *reinterpret_cast<const bf16x8*>(p);
}

// async global->LDS, 16B per lane. LDS dest is wave-uniform base + lane*16.
__device__ __forceinline__ void gl_lds16(const bf16_t* g, bf16_t* l) {
  __builtin_amdgcn_global_load_lds(
      (const __attribute__((address_space(1))) void*)g,
      (__attribute__((address_space(3))) void*)l, 16, 0, 0);
}

__device__ __forceinline__ uint2 shfl2(uint2 v, int src) {
  uint2 r;
  r.x = (unsigned)__shfl((int)v.x, src, 64);
  r.y = (unsigned)__shfl((int)v.y, src, 64);
  return r;
}

template <typename T> __device__ __forceinline__ T cvt_out(float v);
template <> __device__ __forceinline__ float  cvt_out<float >(float v) { return v; }
template <> __device__ __forceinline__ bf16_t cvt_out<bf16_t>(float v) { return (bf16_t)v; }

// ---------------- transpose + cast: in (R,C) fp32 -> out (C,R) bf16 ----------------
__global__ __launch_bounds__(256) void transpose_cast(const float* __restrict__ in,
                                                      bf16_t* __restrict__ out,
                                                      int R, int C) {
  __shared__ float tile[32][33];
  const int c0 = blockIdx.x * 32, r0 = blockIdx.y * 32;
  const int tx = threadIdx.x & 31, ty = threadIdx.x >> 5;
#pragma unroll
  for (int y = ty; y < 32; y += 8)
    tile[y][tx] = in[(size_t)(r0 + y) * C + (c0 + tx)];
  __syncthreads();
#pragma unroll
  for (int y = ty; y < 32; y += 8)
    out[(size_t)(c0 + y) * R + (r0 + tx)] = (bf16_t)tile[tx][y];
}

// -------- LayerNorm row kernel: emits x(bf16), xn(bf16), maskA(float addend) --------
__global__ __launch_bounds__(256) void row_prep(const float* __restrict__ x,
    const float* __restrict__ ln_w, const float* __restrict__ ln_b,
    const int* __restrict__ mask,
    bf16_t* __restrict__ xbf, bf16_t* __restrict__ xn, float* __restrict__ maskA) {
  const int row = blockIdx.x, t = threadIdx.x;
  __shared__ float red[8];
  const float4 xv = *reinterpret_cast<const float4*>(&x[(size_t)row * DM + t * 4]);
  float s  = xv.x + xv.y + xv.z + xv.w;
  float s2 = xv.x * xv.x + xv.y * xv.y + xv.z * xv.z + xv.w * xv.w;
#pragma unroll
  for (int off = 32; off >= 1; off >>= 1) {
    s  += __shfl_xor(s,  off, 64);
    s2 += __shfl_xor(s2, off, 64);
  }
  if ((t & 63) == 0) { red[t >> 6] = s; red[4 + (t >> 6)] = s2; }
  __syncthreads();
  s  = red[0] + red[1] + red[2] + red[3];
  s2 = red[4] + red[5] + red[6] + red[7];
  const float mu   = s * (1.0f / DM);
  const float var  = s2 * (1.0f / DM) - mu * mu;
  const float rstd = rsqrtf(var + 1e-5f);
  const float4 wv = *reinterpret_cast<const float4*>(&ln_w[t * 4]);
  const float4 bv = *reinterpret_cast<const float4*>(&ln_b[t * 4]);
  union { bf16_t h[4]; uint2 u; } p0, p1;
  p0.h[0] = (bf16_t)xv.x; p0.h[1] = (bf16_t)xv.y;
  p0.h[2] = (bf16_t)xv.z; p0.h[3] = (bf16_t)xv.w;
  p1.h[0] = (bf16_t)((xv.x - mu) * rstd * wv.x + bv.x);
  p1.h[1] = (bf16_t)((xv.y - mu) * rstd * wv.y + bv.y);
  p1.h[2] = (bf16_t)((xv.z - mu) * rstd * wv.z + bv.z);
  p1.h[3] = (bf16_t)((xv.w - mu) * rstd * wv.w + bv.w);
  *reinterpret_cast<uint2*>(&xbf[(size_t)row * DM + t * 4]) = p0.u;
  *reinterpret_cast<uint2*>(&xn [(size_t)row * DM + t * 4]) = p1.u;
  if (t == 0) maskA[row] = mask[row] ? 0.0f : -1e30f;
}

// ---- shared 128x128 MFMA core, 1-deep double-buffered LDS, 1 barrier/K-step ----
__device__ __forceinline__ void gemm_core_db(
    const bf16_t* __restrict__ A, const bf16_t* __restrict__ Bt, int K,
    int m0, int n0, bf16_t* As, bf16_t* Bs, f32x4 (&acc)[4][4]) {
  const int t = threadIdx.x, lane = t & 63, w = t >> 6;
  const int wm = (w & 1) * 64, wn = (w >> 1) * 64;
  const int l15 = lane & 15, q4 = lane >> 4;
  const int sr = lane >> 2, sc = (lane & 3) * 8;   // 16 rows x 32 cols per issue
  const bf16_t* Ap0 = A  + (size_t)(m0 + w * 32 + sr) * K + sc;
  const bf16_t* Ap1 = Ap0 + (size_t)16 * K;
  const bf16_t* Bp0 = Bt + (size_t)(n0 + w * 32 + sr) * K + sc;
  const bf16_t* Bp1 = Bp0 + (size_t)16 * K;
  const int la0 = (w * 32) * 32, la1 = (w * 32 + 16) * 32;
  // prologue: stage tile 0 into buf 0
  gl_lds16(Ap0, As + la0);
  gl_lds16(Ap1, As + la1);
  gl_lds16(Bp0, Bs + la0);
  gl_lds16(Bp1, Bs + la1);
  __syncthreads();            // drains vmcnt(0): tile 0 resident
  int buf = 0;
#pragma unroll 1
  for (int k0 = 0; k0 < K; k0 += 32) {
    const int nbuf = buf ^ 1;
    if (k0 + 32 < K) {        // stage next tile into other buffer (stays in flight)
      const int kn = k0 + 32;
      gl_lds16(Ap0 + kn, As + nbuf * (128 * 32) + la0);
      gl_lds16(Ap1 + kn, As + nbuf * (128 * 32) + la1);
      gl_lds16(Bp0 + kn, Bs + nbuf * (128 * 32) + la0);
      gl_lds16(Bp1 + kn, Bs + nbuf * (128 * 32) + la1);
    }
    const bf16_t* Asb = As + buf * (128 * 32);
    const bf16_t* Bsb = Bs + buf * (128 * 32);
    bf16x8 af[4], bfr[4];
#pragma unroll
    for (int mt = 0; mt < 4; ++mt) af[mt]  = ld8(&Asb[(wm + mt * 16 + l15) * 32 + q4 * 8]);
#pragma unroll
    for (int nt = 0; nt < 4; ++nt) bfr[nt] = ld8(&Bsb[(wn + nt * 16 + l15) * 32 + q4 * 8]);
#pragma unroll
    for (int mt = 0; mt < 4; ++mt)
#pragma unroll
      for (int nt = 0; nt < 4; ++nt)
        acc[mt][nt] = __builtin_amdgcn_mfma_f32_16x16x32_bf16(af[mt], bfr[nt], acc[mt][nt], 0, 0, 0);
    __syncthreads();          // one barrier: reads of buf done + next stage landed
    buf = nbuf;
  }
}

// ---- fused q-proj + kv-proj in one dispatch ----
__global__ __launch_bounds__(256) void gemm_qkv(
    const bf16_t* __restrict__ xn,  const bf16_t* __restrict__ wqT,  bf16_t* __restrict__ qb,
    const bf16_t* __restrict__ xbf, const bf16_t* __restrict__ wkvT,
    bf16_t* __restrict__ kkb, bf16_t* __restrict__ vTb) {
  __shared__ alignas(16) bf16_t As[2][128 * 32];
  __shared__ alignas(16) bf16_t Bs[2][128 * 32];
  const int bx = blockIdx.x;
  const bool isKV = (bx < 32);
  const int m0 = isKV ? bx * 128 : ((bx - 32) & 31) * 128;
  const int n0 = isKV ? 0 : ((bx - 32) >> 5) * 128;
  const bf16_t* A  = isKV ? xbf  : xn;
  const bf16_t* Bt = isKV ? wkvT : wqT;
  f32x4 acc[4][4] = {};
  gemm_core_db(A, Bt, DM, m0, n0, &As[0][0], &Bs[0][0], acc);

  const int lane = threadIdx.x & 63, w = threadIdx.x >> 6;
  const int wm = (w & 1) * 64, wn = (w >> 1) * 64;
  const int l15 = lane & 15, q4 = lane >> 4;
#pragma unroll
  for (int mt = 0; mt < 4; ++mt)
#pragma unroll
    for (int nt = 0; nt < 4; ++nt)
#pragma unroll
      for (int r = 0; r < 4; ++r) {
        const int gm = m0 + wm + mt * 16 + q4 * 4 + r;
        const int gn = n0 + wn + nt * 16 + l15;
        if (isKV) {
          const bf16_t ov = (bf16_t)acc[mt][nt][r];
          if (gn < HD) kkb[(size_t)gm * HD + gn] = ov;
          else vTb[((size_t)(gm >> 11) * HD + (gn - HD)) * SEQ + (gm & 2047)] = ov;
        } else {
          qb[(size_t)gm * DM + gn] = (bf16_t)(acc[mt][nt][r] * 0.125f);
        }
      }
}

// ---- out-projection: C(M,1024) fp32 = A(M,1024)*woT(1024,1024)^T ----
__global__ __launch_bounds__(256) void gemm_out(const bf16_t* __restrict__ A,
    const bf16_t* __restrict__ Bt, float* __restrict__ C, int K) {
  __shared__ alignas(16) bf16_t As[2][128 * 32];
  __shared__ alignas(16) bf16_t Bs[2][128 * 32];
  const int m0 = blockIdx.x * 128, n0 = blockIdx.y * 128;
  f32x4 acc[4][4] = {};
  gemm_core_db(A, Bt, K, m0, n0, &As[0][0], &Bs[0][0], acc);
  const int lane = threadIdx.x & 63, w = threadIdx.x >> 6;
  const int wm = (w & 1) * 64, wn = (w >> 1) * 64;
  const int l15 = lane & 15, q4 = lane >> 4;
#pragma unroll
  for (int mt = 0; mt < 4; ++mt)
#pragma unroll
    for (int nt = 0; nt < 4; ++nt)
#pragma unroll
      for (int r = 0; r < 4; ++r) {
        const int gm = m0 + wm + mt * 16 + q4 * 4 + r;
        const int gn = n0 + wn + nt * 16 + l15;
        C[(size_t)gm * DM + gn] = acc[mt][nt][r];
      }
}

// ------- flash attention v4: no LDS, no barriers. K/V MFMA fragments load
//         directly from global (L2-resident: 1 MB total); K regs software-
//         pipelined (reload same regs right after QK consumes them); V issued
//         at iter start, consumed ~500cy later by PV. Waves fully independent.
//         unroll 2: keeps even/odd pipeline without 32x codegen blowup. -------
__global__ __launch_bounds__(256, 3) void flash_attn(
    const bf16_t* __restrict__ q,     // (B, SEQ, DM), head h at cols h*64..
    const bf16_t* __restrict__ kk,    // (B, SEQ, HD)
    const bf16_t* __restrict__ vT,    // (B, HD, SEQ)
    const float*  __restrict__ bias,  // (NHEAD, SEQ, SEQ)
    const float*  __restrict__ maskA, // (B, SEQ): 0 or -1e30
    bf16_t* __restrict__ aout)        // (B, SEQ, DM)
{
  const int b = blockIdx.y & 1, h = blockIdx.y >> 1;  // b fastest: bias L2 reuse
  const int i0 = blockIdx.x * 64;
  const int t = threadIdx.x, lane = t & 63, w = t >> 6;
  const int l15 = lane & 15, q4 = lane >> 4;

  // Q fragments direct from global (B-operand: B[k=dh][n=query=l15])
  const bf16_t* qrow = &q[((size_t)b * SEQ + i0 + w * 16 + l15) * DM + h * HD];
  const bf16x8 bq0 = ld8(qrow + q4 * 8);
  const bf16x8 bq1 = ld8(qrow + 32 + q4 * 8);

  f32x4 o[4] = {};
  float m_run = -1e30f, l_run = 0.0f;

  const float* bias_p = bias + (size_t)h * SEQ * SEQ
                      + (size_t)(i0 + w * 16 + l15) * SEQ + q4 * 4;
  const float* mask_p = maskA + b * SEQ + q4 * 4;

  // K fragment base: A-layout A[row=key=mt*16+l15][k=dh=q4*8+j]
  const bf16_t* kbase = &kk[((size_t)b * SEQ + l15) * HD + q4 * 8];
  // V fragment base: B-layout B[k=key=q4*8+j][n=dh=nt*16+l15] from V^T rows
  const bf16_t* vbase = &vT[((size_t)b * HD + l15) * SEQ + q4 * 8];

  // preload K fragments for iter 0 and fused (bias+mask) for iter 0
  bf16x8 ka[4], kb[4];
#pragma unroll
  for (int mt = 0; mt < 4; ++mt) {
    ka[mt] = ld8(kbase + (size_t)(mt * 16) * HD);
    kb[mt] = ld8(kbase + (size_t)(mt * 16) * HD + 32);
  }
  f32x4 bm[4];
#pragma unroll
  for (int mt = 0; mt < 4; ++mt) {
    const f32x4 bv = *reinterpret_cast<const f32x4*>(bias_p + mt * 16);
    const f32x4 mv = *reinterpret_cast<const f32x4*>(mask_p + mt * 16);
    bm[mt] = bv + mv;
  }

#pragma unroll 2
  for (int it = 0; it < SEQ / 64; ++it) {
    const int j0 = it * 64;
    // next-tile offset; wraps to 0 on last iter (harmless valid reads, uniform)
    const int jn = (it + 1 < SEQ / 64) ? j0 + 64 : 0;

    // issue V fragment loads for THIS tile now; consumed after softmax (~500cy)
    bf16x8 vv0[4], vv1[4];
#pragma unroll
    for (int nt = 0; nt < 4; ++nt) {
      vv0[nt] = ld8(vbase + (size_t)(nt * 16) * SEQ + j0);
      vv1[nt] = ld8(vbase + (size_t)(nt * 16) * SEQ + j0 + 32);
    }

    // S^T: D[m=key][n=query] = K·Q^T  (4 key-subtiles x 2 dh-halves)
    f32x4 s[4];
#pragma unroll
    for (int mt = 0; mt < 4; ++mt) {
      f32x4 z = {0.f, 0.f, 0.f, 0.f};
      z = __builtin_amdgcn_mfma_f32_16x16x32_bf16(ka[mt], bq0, z, 0, 0, 0);
      z = __builtin_amdgcn_mfma_f32_16x16x32_bf16(kb[mt], bq1, z, 0, 0, 0);
      s[mt] = z;
    }

    // reload K fragments for NEXT tile into the same registers (sw pipeline;
    // latency hidden under softmax+PV of this tile)
#pragma unroll
    for (int mt = 0; mt < 4; ++mt) {
      ka[mt] = ld8(kbase + (size_t)(jn + mt * 16) * HD);
      kb[mt] = ld8(kbase + (size_t)(jn + mt * 16) * HD + 32);
    }

    // add fused bias+mask; per-query max over lane's 16 keys
    float mx = -1e30f;
#pragma unroll
    for (int mt = 0; mt < 4; ++mt)
#pragma unroll
      for (int r = 0; r < 4; ++r) {
        s[mt][r] = s[mt][r] + bm[mt][r];
        mx = fmaxf(mx, s[mt][r]);
      }
    // prefetch next fused bias+mask into regs (same regs, reload after use)
#pragma unroll
    for (int mt = 0; mt < 4; ++mt) {
      const f32x4 bv = *reinterpret_cast<const f32x4*>(bias_p + jn + mt * 16);
      const f32x4 mv = *reinterpret_cast<const f32x4*>(mask_p + jn + mt * 16);
      bm[mt] = bv + mv;
    }
    mx = fmaxf(mx, __shfl_xor(mx, 16, 64));
    mx = fmaxf(mx, __shfl_xor(mx, 32, 64));
    const float mnew  = fmaxf(m_run, mx);
    const float alpha = __builtin_amdgcn_exp2f((m_run - mnew) * L2E);
    const float cc    = -mnew * L2E;
    m_run = mnew;

    float su = 0.0f;
#pragma unroll
    for (int mt = 0; mt < 4; ++mt)
#pragma unroll
      for (int r = 0; r < 4; ++r) {
        s[mt][r] = __builtin_amdgcn_exp2f(__builtin_fmaf(s[mt][r], L2E, cc));
        su += s[mt][r];
      }
    su += __shfl_xor(su, 16, 64);
    su += __shfl_xor(su, 32, 64);
    l_run = l_run * alpha + su;

    // rescale O by alpha of query q4*4+r (value uniform across quads)
#pragma unroll
    for (int r = 0; r < 4; ++r) {
      const float a_r = __shfl(alpha, q4 * 4 + r, 64);
      o[0][r] *= a_r; o[1][r] *= a_r; o[2][r] *= a_r; o[3][r] *= a_r;
    }

    // pack P^T (bf16x4 per key-subtile) and transpose to A-layout via shfl
    uint2 pk[4];
#pragma unroll
    for (int mt = 0; mt < 4; ++mt) {
      union { bf16_t hh[4]; uint2 u; } pu;
      pu.hh[0] = (bf16_t)s[mt][0]; pu.hh[1] = (bf16_t)s[mt][1];
      pu.hh[2] = (bf16_t)s[mt][2]; pu.hh[3] = (bf16_t)s[mt][3];
      pk[mt] = pu.u;
    }
    const int src0 = ((q4 & 1) << 5) + l15;   // lane holding keys [base..base+4)
    const int src1 = src0 + 16;               // lane holding keys [base+4..base+8)
    const bool hiSel = (q4 >> 1) != 0;        // which mt group this dest needs
#pragma unroll
    for (int ks = 0; ks < 2; ++ks) {
      const uint2 a0 = shfl2(pk[2 * ks],     src0);
      const uint2 a1 = shfl2(pk[2 * ks + 1], src0);
      const uint2 b0 = shfl2(pk[2 * ks],     src1);
      const uint2 b1 = shfl2(pk[2 * ks + 1], src1);
      union { unsigned u[4]; bf16x8 v; } pf;
      pf.u[0] = hiSel ? a1.x : a0.x; pf.u[1] = hiSel ? a1.y : a0.y;
      pf.u[2] = hiSel ? b1.x : b0.x; pf.u[3] = hiSel ? b1.y : b0.y;
#pragma unroll
      for (int nt = 0; nt < 4; ++nt) {
        const bf16x8 vv = (ks == 0) ? vv0[nt] : vv1[nt];
        o[nt] = __builtin_amdgcn_mfma_f32_16x16x32_bf16(pf.v, vv, o[nt], 0, 0, 0);
      }
    }
  }

#pragma unroll
  for (int r = 0; r < 4; ++r) {
    const float linv = 1.0f / __shfl(l_run, q4 * 4 + r, 64);
    const int gi = i0 + w * 16 + q4 * 4 + r;
    bf16_t* dst = &aout[((size_t)b * SEQ + gi) * DM + h * HD];
#pragma unroll
    for (int nt = 0; nt < 4; ++nt)
      dst[nt * 16 + l15] = (bf16_t)(o[nt][r] * linv);
  }
}

extern "C" void kernel_launch(void* const* d_in, const int* in_sizes, int n_in,
                              void* d_out, int out_size, void* d_ws, size_t ws_size,
                              hipStream_t stream) {
  const float* x         = (const float*)d_in[0];
  const float* attn_bias = (const float*)d_in[1];
  const float* ln_w      = (const float*)d_in[2];
  const float* ln_b      = (const float*)d_in[3];
  const float* wq        = (const float*)d_in[4];
  const float* wkv       = (const float*)d_in[5];
  const float* wo        = (const float*)d_in[6];
  const int*   mask      = (const int*)d_in[7];
  float* out = (float*)d_out;

  char* ws = (char*)d_ws;
  size_t off = 0;
  auto alloc = [&](size_t bytes) {
    char* p = ws + off;
    off += (bytes + 255) & ~(size_t)255;
    return p;
  };
  bf16_t* xbf   = (bf16_t*)alloc((size_t)BB * SEQ * DM * 2);
  bf16_t* xn    = (bf16_t*)alloc((size_t)BB * SEQ * DM * 2);
  bf16_t* wqT   = (bf16_t*)alloc((size_t)DM * DM * 2);
  bf16_t* wkvT  = (bf16_t*)alloc((size_t)2 * HD * DM * 2);
  bf16_t* woT   = (bf16_t*)alloc((size_t)DM * DM * 2);
  bf16_t* qb    = (bf16_t*)alloc((size_t)BB * SEQ * DM * 2);
  bf16_t* kkb   = (bf16_t*)alloc((size_t)BB * SEQ * HD * 2);
  bf16_t* vTb   = (bf16_t*)alloc((size_t)BB * HD * SEQ * 2);
  bf16_t* aoutb = (bf16_t*)alloc((size_t)BB * SEQ * DM * 2);
  float*  maskA = (float*)alloc((size_t)BB * SEQ * 4);

  transpose_cast<<<dim3(DM / 32, DM / 32), 256, 0, stream>>>(wq, wqT, DM, DM);
  transpose_cast<<<dim3(128 / 32, DM / 32), 256, 0, stream>>>(wkv, wkvT, DM, 128);
  transpose_cast<<<dim3(DM / 32, DM / 32), 256, 0, stream>>>(wo, woT, DM, DM);
  row_prep<<<BB * SEQ, 256, 0, stream>>>(x, ln_w, ln_b, mask, xbf, xn, maskA);
  // fused: blocks 0..31 kv = x @ wkv -> K,(V^T); blocks 32..287 q = xn @ wq * 0.125
  gemm_qkv<<<288, 256, 0, stream>>>(xn, wqT, qb, xbf, wkvT, kkb, vTb);
  flash_attn<<<dim3(SEQ / 64, BB * NHEAD), 256, 0, stream>>>(qb, kkb, vTb, attn_bias,
                                                             maskA, aoutb);
  // out = aout @ wo (fp32 output)
  gemm_out<<<dim3(32, 8), 256, 0, stream>>>(aoutb, woT, out, DM);
}

// Round 5
// 479.277 us; speedup vs baseline: 1.4507x; 1.4507x over previous
//
#include <hip/hip_runtime.h>
#include <hip/hip_bf16.h>

typedef __bf16 bf16_t;
typedef __bf16 bf16x4 __attribute__((ext_vector_type(4)));
typedef __bf16 bf16x8 __attribute__((ext_vector_type(8)));
typedef float f32x4 __attribute__((ext_vector_type(4)));

static constexpr int BB    = 2;
static constexpr int SEQ   = 2048;
static constexpr int DM    = 1024;   // D == INNER
static constexpr int NHEAD = 16;
static constexpr int HD    = 64;
static constexpr float L2E = 1.4426950408889634f;

__device__ __forceinline__ bf16x8 ld8(const bf16_t* p) {
  return *reinterpret_cast<const bf16x8*>(p);
}

// async global->LDS, 16B per lane. LDS dest is wave-uniform base + lane*16.
__device__ __forceinline__ void gl_lds16(const bf16_t* g, bf16_t* l) {
  __builtin_amdgcn_global_load_lds(
      (const __attribute__((address_space(1))) void*)g,
      (__attribute__((address_space(3))) void*)l, 16, 0, 0);
}

__device__ __forceinline__ uint2 shfl2(uint2 v, int src) {
  uint2 r;
  r.x = (unsigned)__shfl((int)v.x, src, 64);
  r.y = (unsigned)__shfl((int)v.y, src, 64);
  return r;
}

template <typename T> __device__ __forceinline__ T cvt_out(float v);
template <> __device__ __forceinline__ float  cvt_out<float >(float v) { return v; }
template <> __device__ __forceinline__ bf16_t cvt_out<bf16_t>(float v) { return (bf16_t)v; }

// ---------------- fused prep: 3x transpose_cast + row_prep in ONE dispatch ----------------
// blocks [0,1024): wq(1024x1024)->wqT ; [1024,1152): wkv(1024x128)->wkvT ;
// [1152,2176): wo(1024x1024)->woT ; [2176,6272): row_prep rows 0..4095.
__device__ __forceinline__ void tc_body(const float* __restrict__ in,
                                        bf16_t* __restrict__ out,
                                        int R, int C, int bx, int by,
                                        float (*tile)[33]) {
  const int c0 = bx * 32, r0 = by * 32;
  const int tx = threadIdx.x & 31, ty = threadIdx.x >> 5;
#pragma unroll
  for (int y = ty; y < 32; y += 8)
    tile[y][tx] = in[(size_t)(r0 + y) * C + (c0 + tx)];
  __syncthreads();
#pragma unroll
  for (int y = ty; y < 32; y += 8)
    out[(size_t)(c0 + y) * R + (r0 + tx)] = (bf16_t)tile[tx][y];
}

__device__ __forceinline__ void row_prep_body(int row,
    const float* __restrict__ x, const float* __restrict__ ln_w,
    const float* __restrict__ ln_b, const int* __restrict__ mask,
    bf16_t* __restrict__ xbf, bf16_t* __restrict__ xn, float* __restrict__ maskA,
    float* red) {
  const int t = threadIdx.x;
  const float4 xv = *reinterpret_cast<const float4*>(&x[(size_t)row * DM + t * 4]);
  float s  = xv.x + xv.y + xv.z + xv.w;
  float s2 = xv.x * xv.x + xv.y * xv.y + xv.z * xv.z + xv.w * xv.w;
#pragma unroll
  for (int off = 32; off >= 1; off >>= 1) {
    s  += __shfl_xor(s,  off, 64);
    s2 += __shfl_xor(s2, off, 64);
  }
  if ((t & 63) == 0) { red[t >> 6] = s; red[4 + (t >> 6)] = s2; }
  __syncthreads();
  s  = red[0] + red[1] + red[2] + red[3];
  s2 = red[4] + red[5] + red[6] + red[7];
  const float mu   = s * (1.0f / DM);
  const float var  = s2 * (1.0f / DM) - mu * mu;
  const float rstd = rsqrtf(var + 1e-5f);
  const float4 wv = *reinterpret_cast<const float4*>(&ln_w[t * 4]);
  const float4 bv = *reinterpret_cast<const float4*>(&ln_b[t * 4]);
  union { bf16_t h[4]; uint2 u; } p0, p1;
  p0.h[0] = (bf16_t)xv.x; p0.h[1] = (bf16_t)xv.y;
  p0.h[2] = (bf16_t)xv.z; p0.h[3] = (bf16_t)xv.w;
  p1.h[0] = (bf16_t)((xv.x - mu) * rstd * wv.x + bv.x);
  p1.h[1] = (bf16_t)((xv.y - mu) * rstd * wv.y + bv.y);
  p1.h[2] = (bf16_t)((xv.z - mu) * rstd * wv.z + bv.z);
  p1.h[3] = (bf16_t)((xv.w - mu) * rstd * wv.w + bv.w);
  *reinterpret_cast<uint2*>(&xbf[(size_t)row * DM + t * 4]) = p0.u;
  *reinterpret_cast<uint2*>(&xn [(size_t)row * DM + t * 4]) = p1.u;
  if (t == 0) maskA[row] = mask[row] ? 0.0f : -1e30f;
}

__global__ __launch_bounds__(256) void prep_all(
    const float* __restrict__ x, const float* __restrict__ ln_w,
    const float* __restrict__ ln_b, const int* __restrict__ mask,
    const float* __restrict__ wq, const float* __restrict__ wkv,
    const float* __restrict__ wo,
    bf16_t* __restrict__ xbf, bf16_t* __restrict__ xn, float* __restrict__ maskA,
    bf16_t* __restrict__ wqT, bf16_t* __restrict__ wkvT, bf16_t* __restrict__ woT) {
  __shared__ float tile[32][33];
  __shared__ float red[8];
  const int bid = blockIdx.x;
  if (bid < 1024) {
    tc_body(wq, wqT, DM, DM, bid & 31, bid >> 5, tile);
  } else if (bid < 1152) {
    const int id = bid - 1024;
    tc_body(wkv, wkvT, DM, 128, id & 3, id >> 2, tile);
  } else if (bid < 2176) {
    const int id = bid - 1152;
    tc_body(wo, woT, DM, DM, id & 31, id >> 5, tile);
  } else {
    row_prep_body(bid - 2176, x, ln_w, ln_b, mask, xbf, xn, maskA, red);
  }
}

// ---- shared 128x128 MFMA core, 1-deep double-buffered LDS, 1 barrier/K-step ----
__device__ __forceinline__ void gemm_core_db(
    const bf16_t* __restrict__ A, const bf16_t* __restrict__ Bt, int K,
    int m0, int n0, bf16_t* As, bf16_t* Bs, f32x4 (&acc)[4][4]) {
  const int t = threadIdx.x, lane = t & 63, w = t >> 6;
  const int wm = (w & 1) * 64, wn = (w >> 1) * 64;
  const int l15 = lane & 15, q4 = lane >> 4;
  const int sr = lane >> 2, sc = (lane & 3) * 8;   // 16 rows x 32 cols per issue
  const bf16_t* Ap0 = A  + (size_t)(m0 + w * 32 + sr) * K + sc;
  const bf16_t* Ap1 = Ap0 + (size_t)16 * K;
  const bf16_t* Bp0 = Bt + (size_t)(n0 + w * 32 + sr) * K + sc;
  const bf16_t* Bp1 = Bp0 + (size_t)16 * K;
  const int la0 = (w * 32) * 32, la1 = (w * 32 + 16) * 32;
  // prologue: stage tile 0 into buf 0
  gl_lds16(Ap0, As + la0);
  gl_lds16(Ap1, As + la1);
  gl_lds16(Bp0, Bs + la0);
  gl_lds16(Bp1, Bs + la1);
  __syncthreads();            // drains vmcnt(0): tile 0 resident
  int buf = 0;
#pragma unroll 1
  for (int k0 = 0; k0 < K; k0 += 32) {
    const int nbuf = buf ^ 1;
    if (k0 + 32 < K) {        // stage next tile into other buffer (stays in flight)
      const int kn = k0 + 32;
      gl_lds16(Ap0 + kn, As + nbuf * (128 * 32) + la0);
      gl_lds16(Ap1 + kn, As + nbuf * (128 * 32) + la1);
      gl_lds16(Bp0 + kn, Bs + nbuf * (128 * 32) + la0);
      gl_lds16(Bp1 + kn, Bs + nbuf * (128 * 32) + la1);
    }
    const bf16_t* Asb = As + buf * (128 * 32);
    const bf16_t* Bsb = Bs + buf * (128 * 32);
    bf16x8 af[4], bfr[4];
#pragma unroll
    for (int mt = 0; mt < 4; ++mt) af[mt]  = ld8(&Asb[(wm + mt * 16 + l15) * 32 + q4 * 8]);
#pragma unroll
    for (int nt = 0; nt < 4; ++nt) bfr[nt] = ld8(&Bsb[(wn + nt * 16 + l15) * 32 + q4 * 8]);
#pragma unroll
    for (int mt = 0; mt < 4; ++mt)
#pragma unroll
      for (int nt = 0; nt < 4; ++nt)
        acc[mt][nt] = __builtin_amdgcn_mfma_f32_16x16x32_bf16(af[mt], bfr[nt], acc[mt][nt], 0, 0, 0);
    __syncthreads();          // one barrier: reads of buf done + next stage landed
    buf = nbuf;
  }
}

// ---- fused q-proj + kv-proj in one dispatch ----
__global__ __launch_bounds__(256) void gemm_qkv(
    const bf16_t* __restrict__ xn,  const bf16_t* __restrict__ wqT,  bf16_t* __restrict__ qb,
    const bf16_t* __restrict__ xbf, const bf16_t* __restrict__ wkvT,
    bf16_t* __restrict__ kkb, bf16_t* __restrict__ vTb) {
  __shared__ alignas(16) bf16_t As[2][128 * 32];
  __shared__ alignas(16) bf16_t Bs[2][128 * 32];
  const int bx = blockIdx.x;
  const bool isKV = (bx < 32);
  const int m0 = isKV ? bx * 128 : ((bx - 32) & 31) * 128;
  const int n0 = isKV ? 0 : ((bx - 32) >> 5) * 128;
  const bf16_t* A  = isKV ? xbf  : xn;
  const bf16_t* Bt = isKV ? wkvT : wqT;
  f32x4 acc[4][4] = {};
  gemm_core_db(A, Bt, DM, m0, n0, &As[0][0], &Bs[0][0], acc);

  const int lane = threadIdx.x & 63, w = threadIdx.x >> 6;
  const int wm = (w & 1) * 64, wn = (w >> 1) * 64;
  const int l15 = lane & 15, q4 = lane >> 4;
#pragma unroll
  for (int mt = 0; mt < 4; ++mt)
#pragma unroll
    for (int nt = 0; nt < 4; ++nt)
#pragma unroll
      for (int r = 0; r < 4; ++r) {
        const int gm = m0 + wm + mt * 16 + q4 * 4 + r;
        const int gn = n0 + wn + nt * 16 + l15;
        if (isKV) {
          const bf16_t ov = (bf16_t)acc[mt][nt][r];
          if (gn < HD) kkb[(size_t)gm * HD + gn] = ov;
          else vTb[((size_t)(gm >> 11) * HD + (gn - HD)) * SEQ + (gm & 2047)] = ov;
        } else {
          qb[(size_t)gm * DM + gn] = (bf16_t)(acc[mt][nt][r] * 0.125f);
        }
      }
}

// ---- out-projection: C(M,1024) fp32 = A(M,1024)*woT(1024,1024)^T ----
__global__ __launch_bounds__(256) void gemm_out(const bf16_t* __restrict__ A,
    const bf16_t* __restrict__ Bt, float* __restrict__ C, int K) {
  __shared__ alignas(16) bf16_t As[2][128 * 32];
  __shared__ alignas(16) bf16_t Bs[2][128 * 32];
  const int m0 = blockIdx.x * 128, n0 = blockIdx.y * 128;
  f32x4 acc[4][4] = {};
  gemm_core_db(A, Bt, K, m0, n0, &As[0][0], &Bs[0][0], acc);
  const int lane = threadIdx.x & 63, w = threadIdx.x >> 6;
  const int wm = (w & 1) * 64, wn = (w >> 1) * 64;
  const int l15 = lane & 15, q4 = lane >> 4;
#pragma unroll
  for (int mt = 0; mt < 4; ++mt)
#pragma unroll
    for (int nt = 0; nt < 4; ++nt)
#pragma unroll
      for (int r = 0; r < 4; ++r) {
        const int gm = m0 + wm + mt * 16 + q4 * 4 + r;
        const int gn = n0 + wn + nt * 16 + l15;
        C[(size_t)gm * DM + gn] = acc[mt][nt][r];
      }
}

// ------- flash attention v3 (round-0 exact): S^T orientation, 64 q-rows/block,
//         64-key tiles, LDS double-buffered K/V (1 barrier/iter), shfl P transpose -------
__global__ __launch_bounds__(256, 4) void flash_attn(
    const bf16_t* __restrict__ q,     // (B, SEQ, DM), head h at cols h*64..
    const bf16_t* __restrict__ kk,    // (B, SEQ, HD)
    const bf16_t* __restrict__ vT,    // (B, HD, SEQ)
    const float*  __restrict__ bias,  // (NHEAD, SEQ, SEQ)
    const float*  __restrict__ maskA, // (B, SEQ): 0 or -1e30
    bf16_t* __restrict__ aout)        // (B, SEQ, DM)
{
  const int b = blockIdx.y & 1, h = blockIdx.y >> 1;  // b fastest: bias L2 reuse
  const int i0 = blockIdx.x * 64;
  const int t = threadIdx.x, lane = t & 63, w = t >> 6;
  const int l15 = lane & 15, q4 = lane >> 4;

  __shared__ alignas(16) bf16_t Ks[2][64][72];   // [key][dh]
  __shared__ alignas(16) bf16_t Vs[2][64][72];   // [dh][key]

  // Q fragments direct from global (B-operand: B[k=dh][n=query=l15])
  const bf16_t* qrow = &q[((size_t)b * SEQ + i0 + w * 16 + l15) * DM + h * HD];
  const bf16x8 bq0 = ld8(qrow + q4 * 8);
  const bf16x8 bq1 = ld8(qrow + 32 + q4 * 8);

  f32x4 o[4] = {};
  float m_run = -1e30f, l_run = 0.0f;

  const float* bias_p = bias + (size_t)h * SEQ * SEQ
                      + (size_t)(i0 + w * 16 + l15) * SEQ + q4 * 4;
  const float* mask_p = maskA + b * SEQ + q4 * 4;

  const int sr = t >> 2, sc = (t & 3) * 16;
  const bf16_t* kp = &kk[((size_t)b * SEQ + sr) * HD + sc];
  const bf16_t* vp = &vT[((size_t)b * HD + sr) * SEQ + sc];

  // prologue: tile 0 into buf 0, bias/mask iter-0 into regs
  uint4 kr0 = *reinterpret_cast<const uint4*>(kp);
  uint4 kr1 = *reinterpret_cast<const uint4*>(kp + 8);
  uint4 vr0 = *reinterpret_cast<const uint4*>(vp);
  uint4 vr1 = *reinterpret_cast<const uint4*>(vp + 8);
  f32x4 bv[4], mv[4];
#pragma unroll
  for (int mt = 0; mt < 4; ++mt) {
    bv[mt] = *reinterpret_cast<const f32x4*>(bias_p + mt * 16);
    mv[mt] = *reinterpret_cast<const f32x4*>(mask_p + mt * 16);
  }
  *reinterpret_cast<uint4*>(&Ks[0][sr][sc])     = kr0;
  *reinterpret_cast<uint4*>(&Ks[0][sr][sc + 8]) = kr1;
  *reinterpret_cast<uint4*>(&Vs[0][sr][sc])     = vr0;
  *reinterpret_cast<uint4*>(&Vs[0][sr][sc + 8]) = vr1;
  __syncthreads();

  for (int it = 0; it < SEQ / 64; ++it) {
    const int buf = it & 1;
    const int j1 = (it + 1) * 64;
    const bool more = (j1 < SEQ);
    if (more) {   // prefetch next K/V tile into regs (global, async)
      kr0 = *reinterpret_cast<const uint4*>(kp + (size_t)j1 * HD);
      kr1 = *reinterpret_cast<const uint4*>(kp + (size_t)j1 * HD + 8);
      vr0 = *reinterpret_cast<const uint4*>(vp + j1);
      vr1 = *reinterpret_cast<const uint4*>(vp + j1 + 8);
    }

    // S^T: D[m=key][n=query] = K·Q^T  (4 key-subtiles x 2 dh-halves)
    f32x4 s[4];
#pragma unroll
    for (int mt = 0; mt < 4; ++mt) {
      const bf16x8 a0 = ld8(&Ks[buf][mt * 16 + l15][q4 * 8]);
      const bf16x8 a1 = ld8(&Ks[buf][mt * 16 + l15][32 + q4 * 8]);
      f32x4 z = {0.f, 0.f, 0.f, 0.f};
      z = __builtin_amdgcn_mfma_f32_16x16x32_bf16(a0, bq0, z, 0, 0, 0);
      z = __builtin_amdgcn_mfma_f32_16x16x32_bf16(a1, bq1, z, 0, 0, 0);
      s[mt] = z;
    }

    // add bias + mask (consume current regs); per-query max over lane's 16 keys
    float mx = -1e30f;
#pragma unroll
    for (int mt = 0; mt < 4; ++mt)
#pragma unroll
      for (int r = 0; r < 4; ++r) {
        s[mt][r] = s[mt][r] + bv[mt][r] + mv[mt][r];
        mx = fmaxf(mx, s[mt][r]);
      }
    if (more) {   // prefetch next bias/mask into regs
#pragma unroll
      for (int mt = 0; mt < 4; ++mt) {
        bv[mt] = *reinterpret_cast<const f32x4*>(bias_p + j1 + mt * 16);
        mv[mt] = *reinterpret_cast<const f32x4*>(mask_p + j1 + mt * 16);
      }
    }
    mx = fmaxf(mx, __shfl_xor(mx, 16, 64));
    mx = fmaxf(mx, __shfl_xor(mx, 32, 64));
    const float mnew  = fmaxf(m_run, mx);
    const float alpha = __builtin_amdgcn_exp2f((m_run - mnew) * L2E);
    const float cc    = -mnew * L2E;
    m_run = mnew;

    float su = 0.0f;
#pragma unroll
    for (int mt = 0; mt < 4; ++mt)
#pragma unroll
      for (int r = 0; r < 4; ++r) {
        s[mt][r] = __builtin_amdgcn_exp2f(__builtin_fmaf(s[mt][r], L2E, cc));
        su += s[mt][r];
      }
    su += __shfl_xor(su, 16, 64);
    su += __shfl_xor(su, 32, 64);
    l_run = l_run * alpha + su;

    // rescale O by alpha of query q4*4+r (value uniform across quads)
#pragma unroll
    for (int r = 0; r < 4; ++r) {
      const float a_r = __shfl(alpha, q4 * 4 + r, 64);
      o[0][r] *= a_r; o[1][r] *= a_r; o[2][r] *= a_r; o[3][r] *= a_r;
    }

    // pack P^T (bf16x4 per key-subtile) and transpose to A-layout via shfl
    uint2 pk[4];
#pragma unroll
    for (int mt = 0; mt < 4; ++mt) {
      union { bf16_t hh[4]; uint2 u; } pu;
      pu.hh[0] = (bf16_t)s[mt][0]; pu.hh[1] = (bf16_t)s[mt][1];
      pu.hh[2] = (bf16_t)s[mt][2]; pu.hh[3] = (bf16_t)s[mt][3];
      pk[mt] = pu.u;
    }
    const int src0 = ((q4 & 1) << 5) + l15;   // lane holding keys [base..base+4)
    const int src1 = src0 + 16;               // lane holding keys [base+4..base+8)
    const bool hiSel = (q4 >> 1) != 0;        // which mt group this dest needs
#pragma unroll
    for (int ks = 0; ks < 2; ++ks) {
      const uint2 a0 = shfl2(pk[2 * ks],     src0);
      const uint2 a1 = shfl2(pk[2 * ks + 1], src0);
      const uint2 b0 = shfl2(pk[2 * ks],     src1);
      const uint2 b1 = shfl2(pk[2 * ks + 1], src1);
      union { unsigned u[4]; bf16x8 v; } pf;
      pf.u[0] = hiSel ? a1.x : a0.x; pf.u[1] = hiSel ? a1.y : a0.y;
      pf.u[2] = hiSel ? b1.x : b0.x; pf.u[3] = hiSel ? b1.y : b0.y;
#pragma unroll
      for (int nt = 0; nt < 4; ++nt) {
        const bf16x8 vv = ld8(&Vs[buf][nt * 16 + l15][ks * 32 + q4 * 8]);
        o[nt] = __builtin_amdgcn_mfma_f32_16x16x32_bf16(pf.v, vv, o[nt], 0, 0, 0);
      }
    }

    if (more) {   // store prefetched tile into the other buffer
      *reinterpret_cast<uint4*>(&Ks[buf ^ 1][sr][sc])     = kr0;
      *reinterpret_cast<uint4*>(&Ks[buf ^ 1][sr][sc + 8]) = kr1;
      *reinterpret_cast<uint4*>(&Vs[buf ^ 1][sr][sc])     = vr0;
      *reinterpret_cast<uint4*>(&Vs[buf ^ 1][sr][sc + 8]) = vr1;
    }
    __syncthreads();
  }

#pragma unroll
  for (int r = 0; r < 4; ++r) {
    const float linv = 1.0f / __shfl(l_run, q4 * 4 + r, 64);
    const int gi = i0 + w * 16 + q4 * 4 + r;
    bf16_t* dst = &aout[((size_t)b * SEQ + gi) * DM + h * HD];
#pragma unroll
    for (int nt = 0; nt < 4; ++nt)
      dst[nt * 16 + l15] = (bf16_t)(o[nt][r] * linv);
  }
}

extern "C" void kernel_launch(void* const* d_in, const int* in_sizes, int n_in,
                              void* d_out, int out_size, void* d_ws, size_t ws_size,
                              hipStream_t stream) {
  const float* x         = (const float*)d_in[0];
  const float* attn_bias = (const float*)d_in[1];
  const float* ln_w      = (const float*)d_in[2];
  const float* ln_b      = (const float*)d_in[3];
  const float* wq        = (const float*)d_in[4];
  const float* wkv       = (const float*)d_in[5];
  const float* wo        = (const float*)d_in[6];
  const int*   mask      = (const int*)d_in[7];
  float* out = (float*)d_out;

  char* ws = (char*)d_ws;
  size_t off = 0;
  auto alloc = [&](size_t bytes) {
    char* p = ws + off;
    off += (bytes + 255) & ~(size_t)255;
    return p;
  };
  bf16_t* xbf   = (bf16_t*)alloc((size_t)BB * SEQ * DM * 2);
  bf16_t* xn    = (bf16_t*)alloc((size_t)BB * SEQ * DM * 2);
  bf16_t* wqT   = (bf16_t*)alloc((size_t)DM * DM * 2);
  bf16_t* wkvT  = (bf16_t*)alloc((size_t)2 * HD * DM * 2);
  bf16_t* woT   = (bf16_t*)alloc((size_t)DM * DM * 2);
  bf16_t* qb    = (bf16_t*)alloc((size_t)BB * SEQ * DM * 2);
  bf16_t* kkb   = (bf16_t*)alloc((size_t)BB * SEQ * HD * 2);
  bf16_t* vTb   = (bf16_t*)alloc((size_t)BB * HD * SEQ * 2);
  bf16_t* aoutb = (bf16_t*)alloc((size_t)BB * SEQ * DM * 2);
  float*  maskA = (float*)alloc((size_t)BB * SEQ * 4);

  // one prep dispatch: wq/wkv/wo transposes + layernorm row prep
  prep_all<<<6272, 256, 0, stream>>>(x, ln_w, ln_b, mask, wq, wkv, wo,
                                     xbf, xn, maskA, wqT, wkvT, woT);
  // fused: blocks 0..31 kv = x @ wkv -> K,(V^T); blocks 32..287 q = xn @ wq * 0.125
  gemm_qkv<<<288, 256, 0, stream>>>(xn, wqT, qb, xbf, wkvT, kkb, vTb);
  flash_attn<<<dim3(SEQ / 64, BB * NHEAD), 256, 0, stream>>>(qb, kkb, vTb, attn_bias,
                                                             maskA, aoutb);
  // out = aout @ wo (fp32 output)
  gemm_out<<<dim3(32, 8), 256, 0, stream>>>(aoutb, woT, out, DM);
}